// Round 2
// baseline (2680.568 us; speedup 1.0000x reference)
//
#include <hip/hip_runtime.h>
#include <float.h>

#define NN 100000      // nodes
#define KF 128         // in features
#define NH 4           // heads
#define DF 32          // out feat per head
#define HF 128         // NH*DF
#define NR 3           // relations
#define NEDGE 400000   // edges per relation
#define SLOPE 0.2f

__device__ __forceinline__ void atomicMaxF(float* addr, float v) {
    // works for mixed-sign floats given init = -FLT_MAX
    if (v >= 0.f) atomicMax((int*)addr, __float_as_int(v));
    else          atomicMin((unsigned int*)addr, __float_as_uint(v));
}

__device__ __forceinline__ float lrelu(float v) {
    return v > 0.f ? v : SLOPE * v;
}

// ---------------------------------------------------------------------------
// GEMM h = x @ Wr  (100000x128 @ 128x64-half), fused el/er/m/denom epilogue.
// Block: 256 threads, 64 rows x 64 cols. blockIdx: bit0 = col half.
// ---------------------------------------------------------------------------
__global__ __launch_bounds__(256) void k_gemm(
    const float* __restrict__ x, const float* __restrict__ W,
    const float* __restrict__ al, const float* __restrict__ ar,
    float* __restrict__ h, float* __restrict__ el, float* __restrict__ er,
    float* __restrict__ m, float* __restrict__ den)
{
    __shared__ float sW[KF][64];   // 32 KB: all K, 64-col half
    __shared__ float sX[64][68];   // 17 KB: 64 rows, 64-K half
    const int t = threadIdx.x;
    const int rb = blockIdx.x >> 1;
    const int cb = blockIdx.x & 1;
    const int row0 = rb * 64;
    const int tx = t & 15;         // 4 cols: cb*64 + tx*4 ..
    const int ty = t >> 4;         // 4 rows: ty*4 .. ty*4+3

    // stage W cols [cb*64, cb*64+64), all 128 k rows
    {
        const float4* W4 = (const float4*)W;     // row stride = 32 float4
        float4* sW4 = (float4*)&sW[0][0];
        for (int i = t; i < KF * 16; i += 256) {
            int k = i >> 4, c = i & 15;
            sW4[i] = W4[k * 32 + cb * 16 + c];
        }
    }

    float acc[4][4];
#pragma unroll
    for (int i = 0; i < 4; ++i)
#pragma unroll
        for (int j = 0; j < 4; ++j) acc[i][j] = 0.f;

    for (int kh = 0; kh < 2; ++kh) {
        // stage x rows [row0, row0+64), k in [kh*64, kh*64+64)
        for (int i = t; i < 64 * 16; i += 256) {
            int r = i >> 4, c = i & 15;
            float4 v = make_float4(0.f, 0.f, 0.f, 0.f);
            if (row0 + r < NN)
                v = *(const float4*)&x[(size_t)(row0 + r) * KF + kh * 64 + c * 4];
            *(float4*)&sX[r][c * 4] = v;
        }
        __syncthreads();
#pragma unroll
        for (int k4 = 0; k4 < 16; ++k4) {
            float4 xv[4], wv[4];
#pragma unroll
            for (int i = 0; i < 4; ++i)
                xv[i] = *(const float4*)&sX[ty * 4 + i][k4 * 4];
#pragma unroll
            for (int kk = 0; kk < 4; ++kk)
                wv[kk] = *(const float4*)&sW[kh * 64 + k4 * 4 + kk][tx * 4];
#pragma unroll
            for (int i = 0; i < 4; ++i) {
                acc[i][0] = fmaf(xv[i].x, wv[0].x, acc[i][0]);
                acc[i][0] = fmaf(xv[i].y, wv[1].x, acc[i][0]);
                acc[i][0] = fmaf(xv[i].z, wv[2].x, acc[i][0]);
                acc[i][0] = fmaf(xv[i].w, wv[3].x, acc[i][0]);
                acc[i][1] = fmaf(xv[i].x, wv[0].y, acc[i][1]);
                acc[i][1] = fmaf(xv[i].y, wv[1].y, acc[i][1]);
                acc[i][1] = fmaf(xv[i].z, wv[2].y, acc[i][1]);
                acc[i][1] = fmaf(xv[i].w, wv[3].y, acc[i][1]);
                acc[i][2] = fmaf(xv[i].x, wv[0].z, acc[i][2]);
                acc[i][2] = fmaf(xv[i].y, wv[1].z, acc[i][2]);
                acc[i][2] = fmaf(xv[i].z, wv[2].z, acc[i][2]);
                acc[i][2] = fmaf(xv[i].w, wv[3].z, acc[i][2]);
                acc[i][3] = fmaf(xv[i].x, wv[0].w, acc[i][3]);
                acc[i][3] = fmaf(xv[i].y, wv[1].w, acc[i][3]);
                acc[i][3] = fmaf(xv[i].z, wv[2].w, acc[i][3]);
                acc[i][3] = fmaf(xv[i].w, wv[3].w, acc[i][3]);
            }
        }
        __syncthreads();
    }

    // write h
#pragma unroll
    for (int i = 0; i < 4; ++i) {
        int row = row0 + ty * 4 + i;
        if (row < NN)
            *(float4*)&h[(size_t)row * HF + cb * 64 + tx * 4] =
                make_float4(acc[i][0], acc[i][1], acc[i][2], acc[i][3]);
    }

    // fused el/er (+ m/den init). head = (cb*64 + tx*4)/32
    const int head = cb * 2 + (tx >> 3);
    float4 a_l = *(const float4*)&al[cb * 64 + tx * 4];
    float4 a_r = *(const float4*)&ar[cb * 64 + tx * 4];
#pragma unroll
    for (int i = 0; i < 4; ++i) {
        float pl = acc[i][0] * a_l.x + acc[i][1] * a_l.y + acc[i][2] * a_l.z + acc[i][3] * a_l.w;
        float pr = acc[i][0] * a_r.x + acc[i][1] * a_r.y + acc[i][2] * a_r.z + acc[i][3] * a_r.w;
#pragma unroll
        for (int s2 = 1; s2 < 8; s2 <<= 1) {
            pl += __shfl_xor(pl, s2);
            pr += __shfl_xor(pr, s2);
        }
        if ((tx & 7) == 0) {
            int row = row0 + ty * 4 + i;
            if (row < NN) {
                el[row * NH + head] = pl;
                er[row * NH + head] = pr;
                m[row * NH + head] = -FLT_MAX;
                den[row * NH + head] = 0.f;
            }
        }
    }
}

// ---------------------------------------------------------------------------
// Edge pass A: e = lrelu(el[src] + er[dst]); store; atomic max into m[dst]
// ---------------------------------------------------------------------------
__global__ __launch_bounds__(256) void k_edge_a(
    const int* __restrict__ src, const int* __restrict__ dst,
    const float* __restrict__ el, const float* __restrict__ er,
    float* __restrict__ ebuf, float* __restrict__ m)
{
    int e = blockIdx.x * 256 + threadIdx.x;
    if (e >= NEDGE) return;
    int s = src[e], d = dst[e];
    float4 L = *(const float4*)&el[s * NH];
    float4 R = *(const float4*)&er[d * NH];
    float4 v;
    v.x = lrelu(L.x + R.x);
    v.y = lrelu(L.y + R.y);
    v.z = lrelu(L.z + R.z);
    v.w = lrelu(L.w + R.w);
    *(float4*)&ebuf[(size_t)e * NH] = v;
    atomicMaxF(&m[d * NH + 0], v.x);
    atomicMaxF(&m[d * NH + 1], v.y);
    atomicMaxF(&m[d * NH + 2], v.z);
    atomicMaxF(&m[d * NH + 3], v.w);
}

// ---------------------------------------------------------------------------
// Edge pass B: ex = exp(e - m[dst]); store; atomic add into den[dst]
// ---------------------------------------------------------------------------
__global__ __launch_bounds__(256) void k_edge_b(
    const int* __restrict__ dst, const float* __restrict__ m,
    float* __restrict__ ebuf, float* __restrict__ den)
{
    int e = blockIdx.x * 256 + threadIdx.x;
    if (e >= NEDGE) return;
    int d = dst[e];
    float4 v = *(float4*)&ebuf[(size_t)e * NH];
    float4 mv = *(const float4*)&m[d * NH];
    v.x = __expf(v.x - mv.x);
    v.y = __expf(v.y - mv.y);
    v.z = __expf(v.z - mv.z);
    v.w = __expf(v.w - mv.w);
    *(float4*)&ebuf[(size_t)e * NH] = v;
    atomicAdd(&den[d * NH + 0], v.x);
    atomicAdd(&den[d * NH + 1], v.y);
    atomicAdd(&den[d * NH + 2], v.z);
    atomicAdd(&den[d * NH + 3], v.w);
}

// ---------------------------------------------------------------------------
// Edge pass C: out[dst] += (ex/den[dst]) * h[src].  32 lanes per edge.
// ---------------------------------------------------------------------------
__global__ __launch_bounds__(256) void k_edge_c(
    const int* __restrict__ src, const int* __restrict__ dst,
    const float* __restrict__ ebuf, const float* __restrict__ den,
    const float* __restrict__ h, float* __restrict__ out)
{
    long long gid = (long long)blockIdx.x * 256 + threadIdx.x;
    int e = (int)(gid >> 5);
    int j = (int)(gid & 31);
    if (e >= NEDGE) return;
    int s = src[e], d = dst[e];
    int head = j >> 3;
    float alpha = ebuf[(size_t)e * NH + head] / den[(size_t)d * NH + head];
    float4 hv = *(const float4*)&h[(size_t)s * HF + j * 4];
    float* o = &out[(size_t)d * HF + j * 4];
    atomicAdd(o + 0, alpha * hv.x);
    atomicAdd(o + 1, alpha * hv.y);
    atomicAdd(o + 2, alpha * hv.z);
    atomicAdd(o + 3, alpha * hv.w);
}

// ---------------------------------------------------------------------------
// out init: out[n,k] = sum_r bias[r,k]
// ---------------------------------------------------------------------------
__global__ __launch_bounds__(256) void k_out_init(
    const float* __restrict__ bias, float* __restrict__ out)
{
    long long i = (long long)blockIdx.x * 256 + threadIdx.x;
    if (i >= (long long)NN * HF) return;
    int k = (int)(i & (HF - 1));
    out[i] = bias[k] + bias[HF + k] + bias[2 * HF + k];
}

extern "C" void kernel_launch(void* const* d_in, const int* in_sizes, int n_in,
                              void* d_out, int out_size, void* d_ws, size_t ws_size,
                              hipStream_t stream) {
    const float* x    = (const float*)d_in[0];
    const float* W    = (const float*)d_in[1];   // (3,128,128)
    const float* al   = (const float*)d_in[2];   // (3,4,32)
    const float* ar   = (const float*)d_in[3];
    const float* bias = (const float*)d_in[4];
    const int* ei     = (const int*)d_in[5];     // (3,2,E) int32 (harness converts ints to int32)
    float* out = (float*)d_out;

    char* p = (char*)d_ws;
    float* h    = (float*)p; p += (size_t)NN * HF * 4;   // 51.2 MB
    float* el   = (float*)p; p += (size_t)NN * NH * 4;
    float* er   = (float*)p; p += (size_t)NN * NH * 4;
    float* m    = (float*)p; p += (size_t)NN * NH * 4;
    float* den  = (float*)p; p += (size_t)NN * NH * 4;
    float* ebuf = (float*)p; p += (size_t)NEDGE * NH * 4;

    k_out_init<<<(NN * HF + 255) / 256, 256, 0, stream>>>(bias, out);

    for (int r = 0; r < NR; ++r) {
        const float* Wr = W + (size_t)r * KF * HF;
        const int* src = ei + (size_t)r * 2 * NEDGE;
        const int* dst = src + NEDGE;
        int rowblocks = (NN + 63) / 64;
        k_gemm<<<rowblocks * 2, 256, 0, stream>>>(x, Wr, al + r * HF, ar + r * HF,
                                                  h, el, er, m, den);
        k_edge_a<<<(NEDGE + 255) / 256, 256, 0, stream>>>(src, dst, el, er, ebuf, m);
        k_edge_b<<<(NEDGE + 255) / 256, 256, 0, stream>>>(dst, m, ebuf, den);
        k_edge_c<<<((size_t)NEDGE * 32 + 255) / 256, 256, 0, stream>>>(src, dst, ebuf, den, h, out);
    }
}

// Round 3
// 508.791 us; speedup vs baseline: 5.2685x; 5.2685x over previous
//
#include <hip/hip_runtime.h>
#include <float.h>

#define NN 100000      // nodes
#define KF 128         // in features
#define NH 4           // heads
#define HF 128         // NH*DF
#define NR 3           // relations
#define NEDGE 400000   // edges per relation
#define SLOPE 0.2f

#define SCAN_M (NR * NN)                       // 300000 counters
#define SCAN_NB ((SCAN_M + 1023) / 1024)       // 293 blocks

__device__ __forceinline__ float lrelu(float v) {
    return v > 0.f ? v : SLOPE * v;
}

// ---------------------------------------------------------------------------
// GEMM h = x @ Wr  (100000x128 @ 128x64-half), fused el/er epilogue.
// Block: 256 threads, 64 rows x 64 cols. blockIdx: bit0 = col half.
// ---------------------------------------------------------------------------
__global__ __launch_bounds__(256) void k_gemm(
    const float* __restrict__ x, const float* __restrict__ W,
    const float* __restrict__ al, const float* __restrict__ ar,
    float* __restrict__ h, float* __restrict__ el, float* __restrict__ er)
{
    __shared__ float sW[KF][64];   // 32 KB
    __shared__ float sX[64][68];   // 17 KB
    const int t = threadIdx.x;
    const int rb = blockIdx.x >> 1;
    const int cb = blockIdx.x & 1;
    const int row0 = rb * 64;
    const int tx = t & 15;
    const int ty = t >> 4;

    {
        const float4* W4 = (const float4*)W;
        float4* sW4 = (float4*)&sW[0][0];
        for (int i = t; i < KF * 16; i += 256) {
            int k = i >> 4, c = i & 15;
            sW4[i] = W4[k * 32 + cb * 16 + c];
        }
    }

    float acc[4][4];
#pragma unroll
    for (int i = 0; i < 4; ++i)
#pragma unroll
        for (int j = 0; j < 4; ++j) acc[i][j] = 0.f;

    for (int kh = 0; kh < 2; ++kh) {
        for (int i = t; i < 64 * 16; i += 256) {
            int r = i >> 4, c = i & 15;
            float4 v = make_float4(0.f, 0.f, 0.f, 0.f);
            if (row0 + r < NN)
                v = *(const float4*)&x[(size_t)(row0 + r) * KF + kh * 64 + c * 4];
            *(float4*)&sX[r][c * 4] = v;
        }
        __syncthreads();
#pragma unroll
        for (int k4 = 0; k4 < 16; ++k4) {
            float4 xv[4], wv[4];
#pragma unroll
            for (int i = 0; i < 4; ++i)
                xv[i] = *(const float4*)&sX[ty * 4 + i][k4 * 4];
#pragma unroll
            for (int kk = 0; kk < 4; ++kk)
                wv[kk] = *(const float4*)&sW[kh * 64 + k4 * 4 + kk][tx * 4];
#pragma unroll
            for (int i = 0; i < 4; ++i) {
                acc[i][0] = fmaf(xv[i].x, wv[0].x, acc[i][0]);
                acc[i][0] = fmaf(xv[i].y, wv[1].x, acc[i][0]);
                acc[i][0] = fmaf(xv[i].z, wv[2].x, acc[i][0]);
                acc[i][0] = fmaf(xv[i].w, wv[3].x, acc[i][0]);
                acc[i][1] = fmaf(xv[i].x, wv[0].y, acc[i][1]);
                acc[i][1] = fmaf(xv[i].y, wv[1].y, acc[i][1]);
                acc[i][1] = fmaf(xv[i].z, wv[2].y, acc[i][1]);
                acc[i][1] = fmaf(xv[i].w, wv[3].y, acc[i][1]);
                acc[i][2] = fmaf(xv[i].x, wv[0].z, acc[i][2]);
                acc[i][2] = fmaf(xv[i].y, wv[1].z, acc[i][2]);
                acc[i][2] = fmaf(xv[i].z, wv[2].z, acc[i][2]);
                acc[i][2] = fmaf(xv[i].w, wv[3].z, acc[i][2]);
                acc[i][3] = fmaf(xv[i].x, wv[0].w, acc[i][3]);
                acc[i][3] = fmaf(xv[i].y, wv[1].w, acc[i][3]);
                acc[i][3] = fmaf(xv[i].z, wv[2].w, acc[i][3]);
                acc[i][3] = fmaf(xv[i].w, wv[3].w, acc[i][3]);
            }
        }
        __syncthreads();
    }

#pragma unroll
    for (int i = 0; i < 4; ++i) {
        int row = row0 + ty * 4 + i;
        if (row < NN)
            *(float4*)&h[(size_t)row * HF + cb * 64 + tx * 4] =
                make_float4(acc[i][0], acc[i][1], acc[i][2], acc[i][3]);
    }

    const int head = cb * 2 + (tx >> 3);
    float4 a_l = *(const float4*)&al[cb * 64 + tx * 4];
    float4 a_r = *(const float4*)&ar[cb * 64 + tx * 4];
#pragma unroll
    for (int i = 0; i < 4; ++i) {
        float pl = acc[i][0] * a_l.x + acc[i][1] * a_l.y + acc[i][2] * a_l.z + acc[i][3] * a_l.w;
        float pr = acc[i][0] * a_r.x + acc[i][1] * a_r.y + acc[i][2] * a_r.z + acc[i][3] * a_r.w;
#pragma unroll
        for (int s2 = 1; s2 < 8; s2 <<= 1) {
            pl += __shfl_xor(pl, s2);
            pr += __shfl_xor(pr, s2);
        }
        if ((tx & 7) == 0) {
            int row = row0 + ty * 4 + i;
            if (row < NN) {
                el[row * NH + head] = pl;
                er[row * NH + head] = pr;
            }
        }
    }
}

// ---------------------------------------------------------------------------
// CSR build: count, 3-kernel exclusive scan, fill (src ids sorted by dst)
// ---------------------------------------------------------------------------
__global__ __launch_bounds__(256) void k_count(const int* __restrict__ ei, int* __restrict__ cnt)
{
    int g = blockIdx.x * 256 + threadIdx.x;
    if (g >= NR * NEDGE) return;
    int r = g / NEDGE;
    int e = g - r * NEDGE;
    int d = ei[(size_t)r * 2 * NEDGE + NEDGE + e];
    atomicAdd(&cnt[r * NN + d], 1);
}

__global__ __launch_bounds__(256) void k_scan1(const int* __restrict__ cnt, int* __restrict__ bsum)
{
    __shared__ int lds[256];
    int b = blockIdx.x, t = threadIdx.x;
    int base = b * 1024 + t * 4;
    int4 v = make_int4(0, 0, 0, 0);
    if (base < SCAN_M) v = *(const int4*)&cnt[base];   // SCAN_M % 4 == 0
    lds[t] = v.x + v.y + v.z + v.w;
    __syncthreads();
    for (int o = 128; o > 0; o >>= 1) {
        if (t < o) lds[t] += lds[t + o];
        __syncthreads();
    }
    if (t == 0) bsum[b] = lds[0];
}

__global__ __launch_bounds__(512) void k_scan2(int* __restrict__ bsum)
{
    __shared__ int lds[512];
    int t = threadIdx.x;
    int v = t < SCAN_NB ? bsum[t] : 0;
    lds[t] = v;
    __syncthreads();
    for (int o = 1; o < 512; o <<= 1) {
        int add = t >= o ? lds[t - o] : 0;
        __syncthreads();
        lds[t] += add;
        __syncthreads();
    }
    if (t < SCAN_NB) bsum[t] = lds[t] - v;   // exclusive
}

__global__ __launch_bounds__(256) void k_scan3(
    const int* __restrict__ cnt, const int* __restrict__ bsum,
    int* __restrict__ off, int* __restrict__ woff)
{
    __shared__ int lds[256];
    int b = blockIdx.x, t = threadIdx.x;
    int base = b * 1024 + t * 4;
    int4 v = make_int4(0, 0, 0, 0);
    if (base < SCAN_M) v = *(const int4*)&cnt[base];
    int p1 = v.x, p2 = p1 + v.y, p3 = p2 + v.z, p4 = p3 + v.w;
    lds[t] = p4;
    __syncthreads();
    for (int o = 1; o < 256; o <<= 1) {
        int add = t >= o ? lds[t - o] : 0;
        __syncthreads();
        lds[t] += add;
        __syncthreads();
    }
    int excl = lds[t] - p4;
    int b0 = bsum[b] + excl;
    if (base < SCAN_M) {
        int4 o4 = make_int4(b0, b0 + p1, b0 + p2, b0 + p3);
        *(int4*)&off[base] = o4;
        *(int4*)&woff[base] = o4;
    }
    if (b == 0 && t == 0) off[SCAN_M] = NR * NEDGE;
}

__global__ __launch_bounds__(256) void k_fill(
    const int* __restrict__ ei, int* __restrict__ woff, int* __restrict__ esrc)
{
    int g = blockIdx.x * 256 + threadIdx.x;
    if (g >= NR * NEDGE) return;
    int r = g / NEDGE;
    int e = g - r * NEDGE;
    int s = ei[(size_t)r * 2 * NEDGE + e];
    int d = ei[(size_t)r * 2 * NEDGE + NEDGE + e];
    int pos = atomicAdd(&woff[r * NN + d], 1);
    esrc[pos] = s;
}

// ---------------------------------------------------------------------------
// Gather: one 64-lane wave per node. Online softmax over in-edges, float2/lane.
// off is pre-offset by relation (off + r*NN); esrc global sorted array.
// ---------------------------------------------------------------------------
__global__ __launch_bounds__(256) void k_gather(
    const int* __restrict__ off, const int* __restrict__ esrc,
    const float* __restrict__ el, const float* __restrict__ er,
    const float* __restrict__ h, float* __restrict__ out)
{
    int n = (blockIdx.x * 256 + threadIdx.x) >> 6;
    int lane = threadIdx.x & 63;
    if (n >= NN) return;
    int head = lane >> 4;                  // (lane*2)/32
    float ern = er[n * NH + head];
    int beg = off[n], end = off[n + 1];
    float m = -FLT_MAX, s = 0.f, a0 = 0.f, a1 = 0.f;
    for (int i = beg; i < end; ++i) {
        int sn = esrc[i];
        float ev = lrelu(el[sn * NH + head] + ern);
        float mn = fmaxf(m, ev);
        float sc = __expf(m - mn);
        float p  = __expf(ev - mn);
        float2 hv = *(const float2*)&h[(size_t)sn * HF + lane * 2];
        s  = s * sc + p;
        a0 = a0 * sc + p * hv.x;
        a1 = a1 * sc + p * hv.y;
        m = mn;
    }
    if (s > 0.f) {
        float inv = 1.f / s;
        float2* o = (float2*)&out[(size_t)n * HF + lane * 2];
        float2 ov = *o;
        ov.x += a0 * inv;
        ov.y += a1 * inv;
        *o = ov;
    }
}

// ---------------------------------------------------------------------------
// out init: out[n,k] = sum_r bias[r,k]
// ---------------------------------------------------------------------------
__global__ __launch_bounds__(256) void k_out_init(
    const float* __restrict__ bias, float* __restrict__ out)
{
    long long i = (long long)blockIdx.x * 256 + threadIdx.x;
    if (i >= (long long)NN * HF) return;
    int k = (int)(i & (HF - 1));
    out[i] = bias[k] + bias[HF + k] + bias[2 * HF + k];
}

extern "C" void kernel_launch(void* const* d_in, const int* in_sizes, int n_in,
                              void* d_out, int out_size, void* d_ws, size_t ws_size,
                              hipStream_t stream) {
    const float* x    = (const float*)d_in[0];
    const float* W    = (const float*)d_in[1];   // (3,128,128)
    const float* al   = (const float*)d_in[2];   // (3,4,32)
    const float* ar   = (const float*)d_in[3];
    const float* bias = (const float*)d_in[4];
    const int* ei     = (const int*)d_in[5];     // (3,2,E) int32
    float* out = (float*)d_out;

    char* p = (char*)d_ws;
    float* h    = (float*)p; p += (size_t)NN * HF * 4;        // 51.2 MB
    float* el   = (float*)p; p += (size_t)NR * NN * NH * 4;   // 4.8 MB
    float* er   = (float*)p; p += (size_t)NR * NN * NH * 4;   // 4.8 MB
    int*   cnt  = (int*)p;   p += (size_t)SCAN_M * 4;         // 1.2 MB
    int*   off  = (int*)p;   p += (size_t)(SCAN_M + 4) * 4;   // 1.2 MB
    int*   woff = (int*)p;   p += (size_t)SCAN_M * 4;         // 1.2 MB
    int*   bsum = (int*)p;   p += 4096;
    int*   esrc = (int*)p;   p += (size_t)NR * NEDGE * 4;     // 4.8 MB

    k_out_init<<<(NN * HF + 255) / 256, 256, 0, stream>>>(bias, out);

    // ---- CSR build (all relations at once) ----
    hipMemsetAsync(cnt, 0, (size_t)SCAN_M * 4, stream);
    k_count<<<(NR * NEDGE + 255) / 256, 256, 0, stream>>>(ei, cnt);
    k_scan1<<<SCAN_NB, 256, 0, stream>>>(cnt, bsum);
    k_scan2<<<1, 512, 0, stream>>>(bsum);
    k_scan3<<<SCAN_NB, 256, 0, stream>>>(cnt, bsum, off, woff);
    k_fill<<<(NR * NEDGE + 255) / 256, 256, 0, stream>>>(ei, woff, esrc);

    // ---- per relation: GEMM + gather ----
    int rowblocks = (NN + 63) / 64;
    for (int r = 0; r < NR; ++r) {
        const float* Wr = W + (size_t)r * KF * HF;
        k_gemm<<<rowblocks * 2, 256, 0, stream>>>(x, Wr, al + r * HF, ar + r * HF,
                                                  h, el + (size_t)r * NN * NH,
                                                  er + (size_t)r * NN * NH);
        k_gather<<<(NN * 64 + 255) / 256, 256, 0, stream>>>(
            off + (size_t)r * NN, esrc,
            el + (size_t)r * NN * NH, er + (size_t)r * NN * NH, h, out);
    }
}

// Round 4
// 491.571 us; speedup vs baseline: 5.4531x; 1.0350x over previous
//
#include <hip/hip_runtime.h>
#include <float.h>

#define NN 100000      // nodes
#define KF 128         // in features
#define NH 4           // heads
#define HF 128         // NH*DF
#define NR 3           // relations
#define NEDGE 400000   // edges per relation
#define SLOPE 0.2f

#define NPART 8                                // one dst-partition per XCD
#define PSIZE 12500                            // NN / NPART
#define CHUNK 4096                             // edges per (part,chunk) block
#define NCHUNK ((NEDGE + CHUNK - 1) / CHUNK)   // 98

#define SCAN_M (NR * NN)                       // 300000 counters
#define SCAN_NB ((SCAN_M + 1023) / 1024)       // 293 blocks

__device__ __forceinline__ float lrelu(float v) {
    return v > 0.f ? v : SLOPE * v;
}

// ---------------------------------------------------------------------------
// GEMM h = x @ Wr  (100000x128 @ 128x64-half), fused el/er epilogue.
// ---------------------------------------------------------------------------
__global__ __launch_bounds__(256) void k_gemm(
    const float* __restrict__ x, const float* __restrict__ W,
    const float* __restrict__ al, const float* __restrict__ ar,
    float* __restrict__ h, float* __restrict__ el, float* __restrict__ er)
{
    __shared__ float sW[KF][64];   // 32 KB
    __shared__ float sX[64][68];   // 17 KB
    const int t = threadIdx.x;
    const int rb = blockIdx.x >> 1;
    const int cb = blockIdx.x & 1;
    const int row0 = rb * 64;
    const int tx = t & 15;
    const int ty = t >> 4;

    {
        const float4* W4 = (const float4*)W;
        float4* sW4 = (float4*)&sW[0][0];
        for (int i = t; i < KF * 16; i += 256) {
            int k = i >> 4, c = i & 15;
            sW4[i] = W4[k * 32 + cb * 16 + c];
        }
    }

    float acc[4][4];
#pragma unroll
    for (int i = 0; i < 4; ++i)
#pragma unroll
        for (int j = 0; j < 4; ++j) acc[i][j] = 0.f;

    for (int kh = 0; kh < 2; ++kh) {
        for (int i = t; i < 64 * 16; i += 256) {
            int r = i >> 4, c = i & 15;
            float4 v = make_float4(0.f, 0.f, 0.f, 0.f);
            if (row0 + r < NN)
                v = *(const float4*)&x[(size_t)(row0 + r) * KF + kh * 64 + c * 4];
            *(float4*)&sX[r][c * 4] = v;
        }
        __syncthreads();
#pragma unroll
        for (int k4 = 0; k4 < 16; ++k4) {
            float4 xv[4], wv[4];
#pragma unroll
            for (int i = 0; i < 4; ++i)
                xv[i] = *(const float4*)&sX[ty * 4 + i][k4 * 4];
#pragma unroll
            for (int kk = 0; kk < 4; ++kk)
                wv[kk] = *(const float4*)&sW[kh * 64 + k4 * 4 + kk][tx * 4];
#pragma unroll
            for (int i = 0; i < 4; ++i) {
                acc[i][0] = fmaf(xv[i].x, wv[0].x, acc[i][0]);
                acc[i][0] = fmaf(xv[i].y, wv[1].x, acc[i][0]);
                acc[i][0] = fmaf(xv[i].z, wv[2].x, acc[i][0]);
                acc[i][0] = fmaf(xv[i].w, wv[3].x, acc[i][0]);
                acc[i][1] = fmaf(xv[i].x, wv[0].y, acc[i][1]);
                acc[i][1] = fmaf(xv[i].y, wv[1].y, acc[i][1]);
                acc[i][1] = fmaf(xv[i].z, wv[2].y, acc[i][1]);
                acc[i][1] = fmaf(xv[i].w, wv[3].y, acc[i][1]);
                acc[i][2] = fmaf(xv[i].x, wv[0].z, acc[i][2]);
                acc[i][2] = fmaf(xv[i].y, wv[1].z, acc[i][2]);
                acc[i][2] = fmaf(xv[i].z, wv[2].z, acc[i][2]);
                acc[i][2] = fmaf(xv[i].w, wv[3].z, acc[i][2]);
                acc[i][3] = fmaf(xv[i].x, wv[0].w, acc[i][3]);
                acc[i][3] = fmaf(xv[i].y, wv[1].w, acc[i][3]);
                acc[i][3] = fmaf(xv[i].z, wv[2].w, acc[i][3]);
                acc[i][3] = fmaf(xv[i].w, wv[3].w, acc[i][3]);
            }
        }
        __syncthreads();
    }

#pragma unroll
    for (int i = 0; i < 4; ++i) {
        int row = row0 + ty * 4 + i;
        if (row < NN)
            *(float4*)&h[(size_t)row * HF + cb * 64 + tx * 4] =
                make_float4(acc[i][0], acc[i][1], acc[i][2], acc[i][3]);
    }

    const int head = cb * 2 + (tx >> 3);
    float4 a_l = *(const float4*)&al[cb * 64 + tx * 4];
    float4 a_r = *(const float4*)&ar[cb * 64 + tx * 4];
#pragma unroll
    for (int i = 0; i < 4; ++i) {
        float pl = acc[i][0] * a_l.x + acc[i][1] * a_l.y + acc[i][2] * a_l.z + acc[i][3] * a_l.w;
        float pr = acc[i][0] * a_r.x + acc[i][1] * a_r.y + acc[i][2] * a_r.z + acc[i][3] * a_r.w;
#pragma unroll
        for (int s2 = 1; s2 < 8; s2 <<= 1) {
            pl += __shfl_xor(pl, s2);
            pr += __shfl_xor(pr, s2);
        }
        if ((tx & 7) == 0) {
            int row = row0 + ty * 4 + i;
            if (row < NN) {
                el[row * NH + head] = pl;
                er[row * NH + head] = pr;
            }
        }
    }
}

// ---------------------------------------------------------------------------
// CSR build, XCD-partitioned: block (part = bx&7, chunk = bx>>3, rel = by)
// scans its edge chunk linearly; processes only dst in [part*PSIZE,(part+1)*PSIZE).
// All atomics/writes for a given line then come from one XCD -> no L2 bouncing.
// ---------------------------------------------------------------------------
__global__ __launch_bounds__(256) void k_count(const int* __restrict__ ei, int* __restrict__ cnt)
{
    const int part = blockIdx.x & 7;
    const int chunk = blockIdx.x >> 3;
    const int r = blockIdx.y;
    const int lo = part * PSIZE, hi = lo + PSIZE;
    const int* __restrict__ dstp = ei + (size_t)r * 2 * NEDGE + NEDGE;
    int* __restrict__ cntr = cnt + r * NN;
    const int e0 = chunk * CHUNK + threadIdx.x * 4;
#pragma unroll
    for (int k = 0; k < CHUNK / 1024; ++k) {
        int e = e0 + k * 1024;
        if (e < NEDGE) {  // NEDGE % 4 == 0, e % 4 == 0 -> int4 safe
            int4 d4 = *(const int4*)&dstp[e];
            if (d4.x >= lo && d4.x < hi) atomicAdd(&cntr[d4.x], 1);
            if (d4.y >= lo && d4.y < hi) atomicAdd(&cntr[d4.y], 1);
            if (d4.z >= lo && d4.z < hi) atomicAdd(&cntr[d4.z], 1);
            if (d4.w >= lo && d4.w < hi) atomicAdd(&cntr[d4.w], 1);
        }
    }
}

__global__ __launch_bounds__(256) void k_scan1(const int* __restrict__ cnt, int* __restrict__ bsum)
{
    __shared__ int lds[256];
    int b = blockIdx.x, t = threadIdx.x;
    int base = b * 1024 + t * 4;
    int4 v = make_int4(0, 0, 0, 0);
    if (base < SCAN_M) v = *(const int4*)&cnt[base];   // SCAN_M % 4 == 0
    lds[t] = v.x + v.y + v.z + v.w;
    __syncthreads();
    for (int o = 128; o > 0; o >>= 1) {
        if (t < o) lds[t] += lds[t + o];
        __syncthreads();
    }
    if (t == 0) bsum[b] = lds[0];
}

__global__ __launch_bounds__(512) void k_scan2(int* __restrict__ bsum)
{
    __shared__ int lds[512];
    int t = threadIdx.x;
    int v = t < SCAN_NB ? bsum[t] : 0;
    lds[t] = v;
    __syncthreads();
    for (int o = 1; o < 512; o <<= 1) {
        int add = t >= o ? lds[t - o] : 0;
        __syncthreads();
        lds[t] += add;
        __syncthreads();
    }
    if (t < SCAN_NB) bsum[t] = lds[t] - v;   // exclusive
}

__global__ __launch_bounds__(256) void k_scan3(
    const int* __restrict__ cnt, const int* __restrict__ bsum,
    int* __restrict__ off, int* __restrict__ woff)
{
    __shared__ int lds[256];
    int b = blockIdx.x, t = threadIdx.x;
    int base = b * 1024 + t * 4;
    int4 v = make_int4(0, 0, 0, 0);
    if (base < SCAN_M) v = *(const int4*)&cnt[base];
    int p1 = v.x, p2 = p1 + v.y, p3 = p2 + v.z, p4 = p3 + v.w;
    lds[t] = p4;
    __syncthreads();
    for (int o = 1; o < 256; o <<= 1) {
        int add = t >= o ? lds[t - o] : 0;
        __syncthreads();
        lds[t] += add;
        __syncthreads();
    }
    int excl = lds[t] - p4;
    int b0 = bsum[b] + excl;
    if (base < SCAN_M) {
        int4 o4 = make_int4(b0, b0 + p1, b0 + p2, b0 + p3);
        *(int4*)&off[base] = o4;
        *(int4*)&woff[base] = o4;
    }
    if (b == 0 && t == 0) off[SCAN_M] = NR * NEDGE;
}

__global__ __launch_bounds__(256) void k_fill(
    const int* __restrict__ ei, int* __restrict__ woff, int* __restrict__ esrc)
{
    const int part = blockIdx.x & 7;
    const int chunk = blockIdx.x >> 3;
    const int r = blockIdx.y;
    const int lo = part * PSIZE, hi = lo + PSIZE;
    const int* __restrict__ srcp = ei + (size_t)r * 2 * NEDGE;
    const int* __restrict__ dstp = srcp + NEDGE;
    int* __restrict__ woffr = woff + r * NN;
    const int e0 = chunk * CHUNK + threadIdx.x * 4;
#pragma unroll
    for (int k = 0; k < CHUNK / 1024; ++k) {
        int e = e0 + k * 1024;
        if (e < NEDGE) {
            int4 d4 = *(const int4*)&dstp[e];
            int4 s4 = *(const int4*)&srcp[e];
            if (d4.x >= lo && d4.x < hi) esrc[atomicAdd(&woffr[d4.x], 1)] = s4.x;
            if (d4.y >= lo && d4.y < hi) esrc[atomicAdd(&woffr[d4.y], 1)] = s4.y;
            if (d4.z >= lo && d4.z < hi) esrc[atomicAdd(&woffr[d4.z], 1)] = s4.z;
            if (d4.w >= lo && d4.w < hi) esrc[atomicAdd(&woffr[d4.w], 1)] = s4.w;
        }
    }
}

// ---------------------------------------------------------------------------
// Gather: one 64-lane wave per node. Online softmax over in-edges, float2/lane.
// ---------------------------------------------------------------------------
__global__ __launch_bounds__(256) void k_gather(
    const int* __restrict__ off, const int* __restrict__ esrc,
    const float* __restrict__ el, const float* __restrict__ er,
    const float* __restrict__ h, float* __restrict__ out)
{
    int n = (blockIdx.x * 256 + threadIdx.x) >> 6;
    int lane = threadIdx.x & 63;
    if (n >= NN) return;
    int head = lane >> 4;                  // (lane*2)/32
    float ern = er[n * NH + head];
    int beg = off[n], end = off[n + 1];
    float m = -FLT_MAX, s = 0.f, a0 = 0.f, a1 = 0.f;
    for (int i = beg; i < end; ++i) {
        int sn = esrc[i];
        float ev = lrelu(el[sn * NH + head] + ern);
        float mn = fmaxf(m, ev);
        float sc = __expf(m - mn);
        float p  = __expf(ev - mn);
        float2 hv = *(const float2*)&h[(size_t)sn * HF + lane * 2];
        s  = s * sc + p;
        a0 = a0 * sc + p * hv.x;
        a1 = a1 * sc + p * hv.y;
        m = mn;
    }
    if (s > 0.f) {
        float inv = 1.f / s;
        float2* o = (float2*)&out[(size_t)n * HF + lane * 2];
        float2 ov = *o;
        ov.x += a0 * inv;
        ov.y += a1 * inv;
        *o = ov;
    }
}

// ---------------------------------------------------------------------------
// out init: out[n,k] = sum_r bias[r,k]
// ---------------------------------------------------------------------------
__global__ __launch_bounds__(256) void k_out_init(
    const float* __restrict__ bias, float* __restrict__ out)
{
    long long i = (long long)blockIdx.x * 256 + threadIdx.x;
    if (i >= (long long)NN * HF) return;
    int k = (int)(i & (HF - 1));
    out[i] = bias[k] + bias[HF + k] + bias[2 * HF + k];
}

extern "C" void kernel_launch(void* const* d_in, const int* in_sizes, int n_in,
                              void* d_out, int out_size, void* d_ws, size_t ws_size,
                              hipStream_t stream) {
    const float* x    = (const float*)d_in[0];
    const float* W    = (const float*)d_in[1];   // (3,128,128)
    const float* al   = (const float*)d_in[2];   // (3,4,32)
    const float* ar   = (const float*)d_in[3];
    const float* bias = (const float*)d_in[4];
    const int* ei     = (const int*)d_in[5];     // (3,2,E) int32
    float* out = (float*)d_out;

    char* p = (char*)d_ws;
    float* h    = (float*)p; p += (size_t)NN * HF * 4;        // 51.2 MB
    float* el   = (float*)p; p += (size_t)NR * NN * NH * 4;   // 4.8 MB
    float* er   = (float*)p; p += (size_t)NR * NN * NH * 4;   // 4.8 MB
    int*   cnt  = (int*)p;   p += (size_t)SCAN_M * 4;         // 1.2 MB
    int*   off  = (int*)p;   p += (size_t)(SCAN_M + 4) * 4;   // 1.2 MB
    int*   woff = (int*)p;   p += (size_t)SCAN_M * 4;         // 1.2 MB
    int*   bsum = (int*)p;   p += 4096;
    int*   esrc = (int*)p;   p += (size_t)NR * NEDGE * 4;     // 4.8 MB

    k_out_init<<<(NN * HF + 255) / 256, 256, 0, stream>>>(bias, out);

    // ---- CSR build (XCD-partitioned count + fill) ----
    hipMemsetAsync(cnt, 0, (size_t)SCAN_M * 4, stream);
    dim3 pgrid(NCHUNK * NPART, NR);
    k_count<<<pgrid, 256, 0, stream>>>(ei, cnt);
    k_scan1<<<SCAN_NB, 256, 0, stream>>>(cnt, bsum);
    k_scan2<<<1, 512, 0, stream>>>(bsum);
    k_scan3<<<SCAN_NB, 256, 0, stream>>>(cnt, bsum, off, woff);
    k_fill<<<pgrid, 256, 0, stream>>>(ei, woff, esrc);

    // ---- per relation: GEMM + gather ----
    int rowblocks = (NN + 63) / 64;
    for (int r = 0; r < NR; ++r) {
        const float* Wr = W + (size_t)r * KF * HF;
        k_gemm<<<rowblocks * 2, 256, 0, stream>>>(x, Wr, al + r * HF, ar + r * HF,
                                                  h, el + (size_t)r * NN * NH,
                                                  er + (size_t)r * NN * NH);
        k_gather<<<(NN * 64 + 255) / 256, 256, 0, stream>>>(
            off + (size_t)r * NN, esrc,
            el + (size_t)r * NN * NH, er + (size_t)r * NN * NH, h, out);
    }
}

// Round 5
// 309.109 us; speedup vs baseline: 8.6719x; 1.5903x over previous
//
#include <hip/hip_runtime.h>
#include <float.h>

#define NN 100000      // nodes
#define KF 128         // in features
#define NH 4           // heads
#define HF 128         // NH*DF
#define NR 3           // relations
#define NEDGE 400000   // edges per relation
#define SLOPE 0.2f

#define NPART 8                                // one dst-partition per XCD
#define PSIZE 12500                            // NN / NPART
#define CHUNK 4096
#define NCHUNK ((NEDGE + CHUNK - 1) / CHUNK)   // 98

#define SCAN_M (NR * NN)                       // 300000
#define SCAN_NB ((SCAN_M + 1023) / 1024)       // 293

#define NMT 6256            // 16-row M tiles (100096 rows, 6250 valid)
#define MB 782              // mm grid.x (8 mtiles per block)

typedef short short8 __attribute__((ext_vector_type(8)));
typedef float floatx4 __attribute__((ext_vector_type(4)));

__device__ __forceinline__ float lrelu(float v) { return v > 0.f ? v : SLOPE * v; }

__device__ __forceinline__ unsigned bf16_rne(float x) {
    unsigned u = __float_as_uint(x);
    return (u + 0x7FFFu + ((u >> 16) & 1u)) >> 16;
}

// ---------------------------------------------------------------------------
// v[p][k] = sum_d W[rel][k][head*32+d] * a_side[rel][head][d],  p=rel*8+head*2+side
// ---------------------------------------------------------------------------
__global__ __launch_bounds__(128) void k_prep0(
    const float* __restrict__ W, const float* __restrict__ al,
    const float* __restrict__ ar, float* __restrict__ v)
{
    int p = blockIdx.x;            // 0..23
    int k = threadIdx.x;           // 0..127
    int rel = p >> 3, head = (p >> 1) & 3, side = p & 1;
    const float* a = (side ? ar : al) + rel * 128 + head * 32;
    const float* w = W + (size_t)rel * KF * HF + (size_t)k * HF + head * 32;
    float s = 0.f;
#pragma unroll
    for (int d = 0; d < 32; ++d) s = fmaf(w[d], a[d], s);
    v[p * 128 + k] = s;
}

// ---------------------------------------------------------------------------
// W -> MFMA-fragment-packed bf16 hi/lo planes.
// bpack[(nt*4+ks)*64 + lane], lane = kgroup*16 + col16, 8 contiguous k per lane.
// ---------------------------------------------------------------------------
__global__ __launch_bounds__(256) void k_bpack(
    const float* __restrict__ W, short8* __restrict__ bhi, short8* __restrict__ blo)
{
    int nt = blockIdx.x;           // 0..23 (global col tile of 16)
    int t = threadIdx.x;
    int c16 = t & 15, k0 = (t >> 4) * 8;
    int col = nt * 16 + c16;       // 0..383
    int rel = col >> 7, wc = col & 127;
    int ks = k0 >> 5, kg = (k0 & 31) >> 3;
    int lane = kg * 16 + c16;
    short8 vh, vl;
#pragma unroll
    for (int e = 0; e < 8; ++e) {
        float x = W[(size_t)rel * KF * HF + (size_t)(k0 + e) * HF + wc];
        unsigned rh = bf16_rne(x);
        float lof = x - __uint_as_float(rh << 16);
        vh[e] = (short)rh;
        vl[e] = (short)bf16_rne(lof);
    }
    size_t idx = (size_t)(nt * 4 + ks) * 64 + lane;
    bhi[idx] = vh;
    blo[idx] = vl;
}

// ---------------------------------------------------------------------------
// x -> fragment-packed bf16 hi/lo planes + elr[node][p] = x . v[p]
// One block per 16-row mtile.
// ---------------------------------------------------------------------------
__global__ __launch_bounds__(256) void k_prep(
    const float* __restrict__ x, const float* __restrict__ v,
    short8* __restrict__ xhi, short8* __restrict__ xlo,
    float* __restrict__ elr)
{
    __shared__ float sx[16][132];
    __shared__ float sv[24][132];
    const int mt = blockIdx.x;
    const int t = threadIdx.x;
    const int row0 = mt * 16;
    if (row0 >= NN) {              // pad tiles: zero xpack
        short8 z = {0,0,0,0,0,0,0,0};
        xhi[(size_t)mt * 256 + t] = z;
        xlo[(size_t)mt * 256 + t] = z;
        return;
    }
    {
        int r = t >> 4, c0 = (t & 15) * 8;
        const float4* xr = (const float4*)&x[(size_t)(row0 + r) * KF + c0];
        *(float4*)&sx[r][c0]     = xr[0];
        *(float4*)&sx[r][c0 + 4] = xr[1];
    }
    for (int i = t; i < 24 * 128; i += 256) {
        int p = i >> 7, k = i & 127;
        sv[p][k] = v[i];
    }
    __syncthreads();
    // (a) fragment-pack 8 elems
    {
        int r = t >> 4, c0 = (t & 15) * 8;
        int ks = c0 >> 5, kg = (c0 & 31) >> 3;
        int lane = kg * 16 + r;
        short8 vh, vl;
#pragma unroll
        for (int e = 0; e < 8; ++e) {
            float xv = sx[r][c0 + e];
            unsigned rh = bf16_rne(xv);
            float lof = xv - __uint_as_float(rh << 16);
            vh[e] = (short)rh;
            vl[e] = (short)bf16_rne(lof);
        }
        size_t idx = (size_t)(mt * 4 + ks) * 64 + lane;
        xhi[idx] = vh;
        xlo[idx] = vl;
    }
    // (b) elr: threads 0..127, row = t>>3, p = (t&7) + {0,8,16}
    if (t < 128) {
        int r = t >> 3, j = t & 7;
#pragma unroll
        for (int pi = 0; pi < 3; ++pi) {
            int p = j + pi * 8;
            float s = 0.f;
#pragma unroll 8
            for (int k = 0; k < 128; ++k) s = fmaf(sx[r][k], sv[p][k], s);
            elr[(size_t)(row0 + r) * 32 + p] = s;
        }
    }
}

// ---------------------------------------------------------------------------
// MFMA GEMM: h_bf16[plane=by][row][col] for 128-col tile nt0 = ntbase + by*8.
// Block 256 = 4 waves (2x2), wave tile 64x64, K=128 in 4 steps.
// Split-bf16: acc += Ahi*Bhi + Ahi*Blo + Alo*Bhi.
// ---------------------------------------------------------------------------
__global__ __launch_bounds__(256) void k_mm(
    const short8* __restrict__ xhi, const short8* __restrict__ xlo,
    const short8* __restrict__ bhi, const short8* __restrict__ blo,
    unsigned short* __restrict__ h3, int ntbase)
{
    const int mt0 = blockIdx.x * 8;
    const int nt0 = ntbase + blockIdx.y * 8;
    unsigned short* __restrict__ h = h3 + (size_t)blockIdx.y * NN * HF;
    const int w = threadIdx.x >> 6, lane = threadIdx.x & 63;
    const int wr = w >> 1, wc = w & 1;

    floatx4 zero = {0.f, 0.f, 0.f, 0.f};
    floatx4 acc[4][4];
#pragma unroll
    for (int i = 0; i < 4; ++i)
#pragma unroll
        for (int j = 0; j < 4; ++j) acc[i][j] = zero;

#pragma unroll
    for (int ks = 0; ks < 4; ++ks) {
        short8 ah[4], alo[4], bh[4], bl[4];
#pragma unroll
        for (int i = 0; i < 4; ++i) {
            size_t ai = (size_t)((mt0 + wr * 4 + i) * 4 + ks) * 64 + lane;
            ah[i]  = xhi[ai];
            alo[i] = xlo[ai];
            size_t bi = (size_t)((nt0 + wc * 4 + i) * 4 + ks) * 64 + lane;
            bh[i] = bhi[bi];
            bl[i] = blo[bi];
        }
#pragma unroll
        for (int i = 0; i < 4; ++i)
#pragma unroll
            for (int j = 0; j < 4; ++j) {
                acc[i][j] = __builtin_amdgcn_mfma_f32_16x16x32_bf16(ah[i],  bh[j], acc[i][j], 0, 0, 0);
                acc[i][j] = __builtin_amdgcn_mfma_f32_16x16x32_bf16(ah[i],  bl[j], acc[i][j], 0, 0, 0);
                acc[i][j] = __builtin_amdgcn_mfma_f32_16x16x32_bf16(alo[i], bh[j], acc[i][j], 0, 0, 0);
            }
    }

    // C/D layout: col = lane&15, row = (lane>>4)*4 + reg  (m89-verified)
#pragma unroll
    for (int i = 0; i < 4; ++i) {
        int rowb = (mt0 + wr * 4 + i) * 16 + (lane >> 4) * 4;
#pragma unroll
        for (int j = 0; j < 4; ++j) {
            int cc = (wc * 4 + j) * 16 + (lane & 15);
#pragma unroll
            for (int rg = 0; rg < 4; ++rg) {
                int row = rowb + rg;
                if (row < NN)
                    h[(size_t)row * HF + cc] = (unsigned short)bf16_rne(acc[i][j][rg]);
            }
        }
    }
}

// ---------------------------------------------------------------------------
// CSR build (XCD-partitioned), unchanged from round 4
// ---------------------------------------------------------------------------
__global__ __launch_bounds__(256) void k_count(const int* __restrict__ ei, int* __restrict__ cnt)
{
    const int part = blockIdx.x & 7;
    const int chunk = blockIdx.x >> 3;
    const int r = blockIdx.y;
    const int lo = part * PSIZE, hi = lo + PSIZE;
    const int* __restrict__ dstp = ei + (size_t)r * 2 * NEDGE + NEDGE;
    int* __restrict__ cntr = cnt + r * NN;
    const int e0 = chunk * CHUNK + threadIdx.x * 4;
#pragma unroll
    for (int k = 0; k < CHUNK / 1024; ++k) {
        int e = e0 + k * 1024;
        if (e < NEDGE) {
            int4 d4 = *(const int4*)&dstp[e];
            if (d4.x >= lo && d4.x < hi) atomicAdd(&cntr[d4.x], 1);
            if (d4.y >= lo && d4.y < hi) atomicAdd(&cntr[d4.y], 1);
            if (d4.z >= lo && d4.z < hi) atomicAdd(&cntr[d4.z], 1);
            if (d4.w >= lo && d4.w < hi) atomicAdd(&cntr[d4.w], 1);
        }
    }
}

__global__ __launch_bounds__(256) void k_scan1(const int* __restrict__ cnt, int* __restrict__ bsum)
{
    __shared__ int lds[256];
    int b = blockIdx.x, t = threadIdx.x;
    int base = b * 1024 + t * 4;
    int4 v = make_int4(0, 0, 0, 0);
    if (base < SCAN_M) v = *(const int4*)&cnt[base];
    lds[t] = v.x + v.y + v.z + v.w;
    __syncthreads();
    for (int o = 128; o > 0; o >>= 1) {
        if (t < o) lds[t] += lds[t + o];
        __syncthreads();
    }
    if (t == 0) bsum[b] = lds[0];
}

__global__ __launch_bounds__(512) void k_scan2(int* __restrict__ bsum)
{
    __shared__ int lds[512];
    int t = threadIdx.x;
    int v = t < SCAN_NB ? bsum[t] : 0;
    lds[t] = v;
    __syncthreads();
    for (int o = 1; o < 512; o <<= 1) {
        int add = t >= o ? lds[t - o] : 0;
        __syncthreads();
        lds[t] += add;
        __syncthreads();
    }
    if (t < SCAN_NB) bsum[t] = lds[t] - v;
}

__global__ __launch_bounds__(256) void k_scan3(
    const int* __restrict__ cnt, const int* __restrict__ bsum,
    int* __restrict__ off, int* __restrict__ woff)
{
    __shared__ int lds[256];
    int b = blockIdx.x, t = threadIdx.x;
    int base = b * 1024 + t * 4;
    int4 v = make_int4(0, 0, 0, 0);
    if (base < SCAN_M) v = *(const int4*)&cnt[base];
    int p1 = v.x, p2 = p1 + v.y, p3 = p2 + v.z, p4 = p3 + v.w;
    lds[t] = p4;
    __syncthreads();
    for (int o = 1; o < 256; o <<= 1) {
        int add = t >= o ? lds[t - o] : 0;
        __syncthreads();
        lds[t] += add;
        __syncthreads();
    }
    int excl = lds[t] - p4;
    int b0 = bsum[b] + excl;
    if (base < SCAN_M) {
        int4 o4 = make_int4(b0, b0 + p1, b0 + p2, b0 + p3);
        *(int4*)&off[base] = o4;
        *(int4*)&woff[base] = o4;
    }
    if (b == 0 && t == 0) off[SCAN_M] = NR * NEDGE;
}

__global__ __launch_bounds__(256) void k_fill(
    const int* __restrict__ ei, int* __restrict__ woff, int* __restrict__ esrc)
{
    const int part = blockIdx.x & 7;
    const int chunk = blockIdx.x >> 3;
    const int r = blockIdx.y;
    const int lo = part * PSIZE, hi = lo + PSIZE;
    const int* __restrict__ srcp = ei + (size_t)r * 2 * NEDGE;
    const int* __restrict__ dstp = srcp + NEDGE;
    int* __restrict__ woffr = woff + r * NN;
    const int e0 = chunk * CHUNK + threadIdx.x * 4;
#pragma unroll
    for (int k = 0; k < CHUNK / 1024; ++k) {
        int e = e0 + k * 1024;
        if (e < NEDGE) {
            int4 d4 = *(const int4*)&dstp[e];
            int4 s4 = *(const int4*)&srcp[e];
            if (d4.x >= lo && d4.x < hi) esrc[atomicAdd(&woffr[d4.x], 1)] = s4.x;
            if (d4.y >= lo && d4.y < hi) esrc[atomicAdd(&woffr[d4.y], 1)] = s4.y;
            if (d4.z >= lo && d4.z < hi) esrc[atomicAdd(&woffr[d4.z], 1)] = s4.z;
            if (d4.w >= lo && d4.w < hi) esrc[atomicAdd(&woffr[d4.w], 1)] = s4.w;
        }
    }
}

// ---------------------------------------------------------------------------
// Fused gather: 2 nodes per wave (32 lanes x ushort4 cols of bf16 h).
// Loops relations [r0,r1): online softmax per relation, accumulate.
// initmode: out = acc + sum_r bias, else out += acc.
// ---------------------------------------------------------------------------
__global__ __launch_bounds__(256) void k_gather(
    const int* __restrict__ off, const int* __restrict__ esrc,
    const float* __restrict__ elr, const unsigned short* __restrict__ h3,
    const float* __restrict__ bias, float* __restrict__ out,
    int r0, int r1, int initmode)
{
    int n = (blockIdx.x * 256 + threadIdx.x) >> 5;
    int l = threadIdx.x & 31;
    if (n >= NN) return;
    int head = l >> 3;
    int c = l * 4;
    float o0 = 0.f, o1 = 0.f, o2 = 0.f, o3 = 0.f;
    for (int r = r0; r < r1; ++r) {
        int pb = r * 8 + head * 2;
        float ern = elr[(size_t)n * 32 + pb + 1];
        const unsigned short* hr = h3 + (size_t)(r - r0) * NN * HF;
        int beg = off[r * NN + n], end = off[r * NN + n + 1];
        float m = -FLT_MAX, s = 0.f, a0 = 0.f, a1 = 0.f, a2 = 0.f, a3 = 0.f;
        for (int i = beg; i < end; ++i) {
            int sn = esrc[i];
            float ev = lrelu(elr[(size_t)sn * 32 + pb] + ern);
            float mn = fmaxf(m, ev);
            float sc = __expf(m - mn);
            float pw = __expf(ev - mn);
            ushort4 hv = *(const ushort4*)&hr[(size_t)sn * HF + c];
            float h0 = __uint_as_float((unsigned)hv.x << 16);
            float h1 = __uint_as_float((unsigned)hv.y << 16);
            float h2 = __uint_as_float((unsigned)hv.z << 16);
            float h3f = __uint_as_float((unsigned)hv.w << 16);
            s  = s  * sc + pw;
            a0 = a0 * sc + pw * h0;
            a1 = a1 * sc + pw * h1;
            a2 = a2 * sc + pw * h2;
            a3 = a3 * sc + pw * h3f;
            m = mn;
        }
        if (s > 0.f) {
            float inv = 1.f / s;
            o0 += a0 * inv; o1 += a1 * inv; o2 += a2 * inv; o3 += a3 * inv;
        }
    }
    float* po = &out[(size_t)n * HF + c];
    if (initmode) {
        float4 b0 = *(const float4*)&bias[c];
        float4 b1 = *(const float4*)&bias[HF + c];
        float4 b2 = *(const float4*)&bias[2 * HF + c];
        float4 ov;
        ov.x = o0 + b0.x + b1.x + b2.x;
        ov.y = o1 + b0.y + b1.y + b2.y;
        ov.z = o2 + b0.z + b1.z + b2.z;
        ov.w = o3 + b0.w + b1.w + b2.w;
        *(float4*)po = ov;
    } else {
        float4 ov = *(float4*)po;
        ov.x += o0; ov.y += o1; ov.z += o2; ov.w += o3;
        *(float4*)po = ov;
    }
}

__global__ __launch_bounds__(256) void k_bail(float* __restrict__ out)
{
    long long i = (long long)blockIdx.x * 256 + threadIdx.x;
    if (i < (long long)NN * HF) out[i] = 0.f;
}

extern "C" void kernel_launch(void* const* d_in, const int* in_sizes, int n_in,
                              void* d_out, int out_size, void* d_ws, size_t ws_size,
                              hipStream_t stream) {
    const float* x    = (const float*)d_in[0];
    const float* W    = (const float*)d_in[1];
    const float* al   = (const float*)d_in[2];
    const float* ar   = (const float*)d_in[3];
    const float* bias = (const float*)d_in[4];
    const int* ei     = (const int*)d_in[5];
    float* out = (float*)d_out;

    const size_t HPLANE = (size_t)NN * HF;            // elems (ushort)
    const size_t XP = (size_t)NMT * 256;              // short8 per plane
    const size_t BP = (size_t)24 * 4 * 64;            // short8 per plane
    const size_t fixed = XP * 16 * 2 + (size_t)NN * 32 * 4 + 24 * 128 * 4 + BP * 16 * 2
                       + (size_t)SCAN_M * 4 + (size_t)(SCAN_M + 4) * 4 + (size_t)SCAN_M * 4
                       + 4096 + (size_t)NR * NEDGE * 4;
    const size_t need_big = fixed + 3 * HPLANE * 2;
    const size_t need_small = fixed + HPLANE * 2;
    if (ws_size < need_small) {
        k_bail<<<(NN * HF + 255) / 256, 256, 0, stream>>>(out);
        return;
    }
    const bool big = ws_size >= need_big;
    const int hplanes = big ? 3 : 1;

    char* p = (char*)d_ws;
    unsigned short* h3 = (unsigned short*)p; p += (size_t)hplanes * HPLANE * 2;
    short8* xhi = (short8*)p; p += XP * 16;
    short8* xlo = (short8*)p; p += XP * 16;
    float*  elr = (float*)p;  p += (size_t)NN * 32 * 4;
    float*  v   = (float*)p;  p += 24 * 128 * 4;
    short8* bhi = (short8*)p; p += BP * 16;
    short8* blo = (short8*)p; p += BP * 16;
    int* cnt  = (int*)p; p += (size_t)SCAN_M * 4;
    int* off  = (int*)p; p += (size_t)(SCAN_M + 4) * 4;
    int* woff = (int*)p; p += (size_t)SCAN_M * 4;
    int* bsum = (int*)p; p += 4096;
    int* esrc = (int*)p; p += (size_t)NR * NEDGE * 4;

    // prep: v, W-pack, x-pack + elr
    k_prep0<<<24, 128, 0, stream>>>(W, al, ar, v);
    k_bpack<<<24, 256, 0, stream>>>(W, bhi, blo);
    k_prep<<<NMT, 256, 0, stream>>>(x, v, xhi, xlo, elr);

    // CSR build
    hipMemsetAsync(cnt, 0, (size_t)SCAN_M * 4, stream);
    dim3 pgrid(NCHUNK * NPART, NR);
    k_count<<<pgrid, 256, 0, stream>>>(ei, cnt);
    k_scan1<<<SCAN_NB, 256, 0, stream>>>(cnt, bsum);
    k_scan2<<<1, 512, 0, stream>>>(bsum);
    k_scan3<<<SCAN_NB, 256, 0, stream>>>(cnt, bsum, off, woff);
    k_fill<<<pgrid, 256, 0, stream>>>(ei, woff, esrc);

    int gblocks = (NN * 32 + 255) / 256;
    if (big) {
        dim3 mmg(MB, 3);
        k_mm<<<mmg, 256, 0, stream>>>(xhi, xlo, bhi, blo, h3, 0);
        k_gather<<<gblocks, 256, 0, stream>>>(off, esrc, elr, h3, bias, out, 0, 3, 1);
    } else {
        for (int r = 0; r < NR; ++r) {
            dim3 mmg(MB, 1);
            k_mm<<<mmg, 256, 0, stream>>>(xhi, xlo, bhi, blo, h3, r * 8);
            k_gather<<<gblocks, 256, 0, stream>>>(off, esrc, elr, h3, bias, out,
                                                  r, r + 1, r == 0 ? 1 : 0);
        }
    }
}

// Round 6
// 279.548 us; speedup vs baseline: 9.5889x; 1.1057x over previous
//
#include <hip/hip_runtime.h>
#include <float.h>

#define NN 100000      // nodes
#define KF 128         // in features
#define NH 4           // heads
#define HF 128         // NH*DF
#define NR 3           // relations
#define NEDGE 400000   // edges per relation
#define SLOPE 0.2f

#define NPART 8                                // one dst-partition per XCD
#define PSIZE 12500                            // NN / NPART
#define CHUNK 4096
#define NCHUNK ((NEDGE + CHUNK - 1) / CHUNK)   // 98

#define SCAN_M (NR * NN)                       // 300000
#define SCAN_NB ((SCAN_M + 1023) / 1024)       // 293

#define NMT 6256            // 16-row M tiles (100096 rows, 6250 valid)
#define MB 782              // mm grid.x (8 mtiles per block)

typedef short short8 __attribute__((ext_vector_type(8)));
typedef float floatx4 __attribute__((ext_vector_type(4)));
typedef unsigned short ushort8_t __attribute__((ext_vector_type(8)));

__device__ __forceinline__ unsigned bf16_rne(float x) {
    unsigned u = __float_as_uint(x);
    return (u + 0x7FFFu + ((u >> 16) & 1u)) >> 16;
}

// ---------------------------------------------------------------------------
// v[p][k] = sum_d W[rel][k][head*32+d] * a_side[rel][head][d],  p=rel*8+head*2+side
// ---------------------------------------------------------------------------
__global__ __launch_bounds__(128) void k_prep0(
    const float* __restrict__ W, const float* __restrict__ al,
    const float* __restrict__ ar, float* __restrict__ v)
{
    int p = blockIdx.x;            // 0..23
    int k = threadIdx.x;           // 0..127
    int rel = p >> 3, head = (p >> 1) & 3, side = p & 1;
    const float* a = (side ? ar : al) + rel * 128 + head * 32;
    const float* w = W + (size_t)rel * KF * HF + (size_t)k * HF + head * 32;
    float s = 0.f;
#pragma unroll
    for (int d = 0; d < 32; ++d) s = fmaf(w[d], a[d], s);
    v[p * 128 + k] = s;
}

// ---------------------------------------------------------------------------
// W -> MFMA-fragment-packed bf16 hi/lo planes.
// ---------------------------------------------------------------------------
__global__ __launch_bounds__(256) void k_bpack(
    const float* __restrict__ W, short8* __restrict__ bhi, short8* __restrict__ blo)
{
    int nt = blockIdx.x;           // 0..23 (global col tile of 16)
    int t = threadIdx.x;
    int c16 = t & 15, k0 = (t >> 4) * 8;
    int col = nt * 16 + c16;       // 0..383
    int rel = col >> 7, wc = col & 127;
    int ks = k0 >> 5, kg = (k0 & 31) >> 3;
    int lane = kg * 16 + c16;
    short8 vh, vl;
#pragma unroll
    for (int e = 0; e < 8; ++e) {
        float x = W[(size_t)rel * KF * HF + (size_t)(k0 + e) * HF + wc];
        unsigned rh = bf16_rne(x);
        float lof = x - __uint_as_float(rh << 16);
        vh[e] = (short)rh;
        vl[e] = (short)bf16_rne(lof);
    }
    size_t idx = (size_t)(nt * 4 + ks) * 64 + lane;
    bhi[idx] = vh;
    blo[idx] = vl;
}

// ---------------------------------------------------------------------------
// x -> fragment-packed bf16 hi/lo planes + elr[node][p] = x . v[p]
// ---------------------------------------------------------------------------
__global__ __launch_bounds__(256) void k_prep(
    const float* __restrict__ x, const float* __restrict__ v,
    short8* __restrict__ xhi, short8* __restrict__ xlo,
    float* __restrict__ elr)
{
    __shared__ float sx[16][132];
    __shared__ float sv[24][132];
    const int mt = blockIdx.x;
    const int t = threadIdx.x;
    const int row0 = mt * 16;
    if (row0 >= NN) {              // pad tiles: zero xpack
        short8 z = {0,0,0,0,0,0,0,0};
        xhi[(size_t)mt * 256 + t] = z;
        xlo[(size_t)mt * 256 + t] = z;
        return;
    }
    {
        int r = t >> 4, c0 = (t & 15) * 8;
        const float4* xr = (const float4*)&x[(size_t)(row0 + r) * KF + c0];
        *(float4*)&sx[r][c0]     = xr[0];
        *(float4*)&sx[r][c0 + 4] = xr[1];
    }
    for (int i = t; i < 24 * 128; i += 256) {
        int p = i >> 7, k = i & 127;
        sv[p][k] = v[i];
    }
    __syncthreads();
    // (a) fragment-pack 8 elems
    {
        int r = t >> 4, c0 = (t & 15) * 8;
        int ks = c0 >> 5, kg = (c0 & 31) >> 3;
        int lane = kg * 16 + r;
        short8 vh, vl;
#pragma unroll
        for (int e = 0; e < 8; ++e) {
            float xv = sx[r][c0 + e];
            unsigned rh = bf16_rne(xv);
            float lof = xv - __uint_as_float(rh << 16);
            vh[e] = (short)rh;
            vl[e] = (short)bf16_rne(lof);
        }
        size_t idx = (size_t)(mt * 4 + ks) * 64 + lane;
        xhi[idx] = vh;
        xlo[idx] = vl;
    }
    // (b) elr: 384 (row,p) items over 256 threads
    for (int it = t; it < 16 * 24; it += 256) {
        int r = it / 24, p = it - r * 24;
        float s = 0.f;
#pragma unroll 8
        for (int k = 0; k < 128; ++k) s = fmaf(sx[r][k], sv[p][k], s);
        elr[(size_t)(row0 + r) * 32 + p] = s;
    }
}

// ---------------------------------------------------------------------------
// MFMA GEMM: split-bf16, wave tile 64x64, K=128 in 4 steps.
// ---------------------------------------------------------------------------
__global__ __launch_bounds__(256) void k_mm(
    const short8* __restrict__ xhi, const short8* __restrict__ xlo,
    const short8* __restrict__ bhi, const short8* __restrict__ blo,
    unsigned short* __restrict__ h3, int ntbase)
{
    const int mt0 = blockIdx.x * 8;
    const int nt0 = ntbase + blockIdx.y * 8;
    unsigned short* __restrict__ h = h3 + (size_t)blockIdx.y * NN * HF;
    const int w = threadIdx.x >> 6, lane = threadIdx.x & 63;
    const int wr = w >> 1, wc = w & 1;

    floatx4 zero = {0.f, 0.f, 0.f, 0.f};
    floatx4 acc[4][4];
#pragma unroll
    for (int i = 0; i < 4; ++i)
#pragma unroll
        for (int j = 0; j < 4; ++j) acc[i][j] = zero;

#pragma unroll
    for (int ks = 0; ks < 4; ++ks) {
        short8 ah[4], alo[4], bh[4], bl[4];
#pragma unroll
        for (int i = 0; i < 4; ++i) {
            size_t ai = (size_t)((mt0 + wr * 4 + i) * 4 + ks) * 64 + lane;
            ah[i]  = xhi[ai];
            alo[i] = xlo[ai];
            size_t bi = (size_t)((nt0 + wc * 4 + i) * 4 + ks) * 64 + lane;
            bh[i] = bhi[bi];
            bl[i] = blo[bi];
        }
#pragma unroll
        for (int i = 0; i < 4; ++i)
#pragma unroll
            for (int j = 0; j < 4; ++j) {
                acc[i][j] = __builtin_amdgcn_mfma_f32_16x16x32_bf16(ah[i],  bh[j], acc[i][j], 0, 0, 0);
                acc[i][j] = __builtin_amdgcn_mfma_f32_16x16x32_bf16(ah[i],  bl[j], acc[i][j], 0, 0, 0);
                acc[i][j] = __builtin_amdgcn_mfma_f32_16x16x32_bf16(alo[i], bh[j], acc[i][j], 0, 0, 0);
            }
    }

    // C/D layout: col = lane&15, row = (lane>>4)*4 + reg
#pragma unroll
    for (int i = 0; i < 4; ++i) {
        int rowb = (mt0 + wr * 4 + i) * 16 + (lane >> 4) * 4;
#pragma unroll
        for (int j = 0; j < 4; ++j) {
            int cc = (wc * 4 + j) * 16 + (lane & 15);
#pragma unroll
            for (int rg = 0; rg < 4; ++rg) {
                int row = rowb + rg;
                if (row < NN)
                    h[(size_t)row * HF + cc] = (unsigned short)bf16_rne(acc[i][j][rg]);
            }
        }
    }
}

// ---------------------------------------------------------------------------
// CSR build (XCD-partitioned)
// ---------------------------------------------------------------------------
__global__ __launch_bounds__(256) void k_count(const int* __restrict__ ei, int* __restrict__ cnt)
{
    const int part = blockIdx.x & 7;
    const int chunk = blockIdx.x >> 3;
    const int r = blockIdx.y;
    const int lo = part * PSIZE, hi = lo + PSIZE;
    const int* __restrict__ dstp = ei + (size_t)r * 2 * NEDGE + NEDGE;
    int* __restrict__ cntr = cnt + r * NN;
    const int e0 = chunk * CHUNK + threadIdx.x * 4;
#pragma unroll
    for (int k = 0; k < CHUNK / 1024; ++k) {
        int e = e0 + k * 1024;
        if (e < NEDGE) {
            int4 d4 = *(const int4*)&dstp[e];
            if (d4.x >= lo && d4.x < hi) atomicAdd(&cntr[d4.x], 1);
            if (d4.y >= lo && d4.y < hi) atomicAdd(&cntr[d4.y], 1);
            if (d4.z >= lo && d4.z < hi) atomicAdd(&cntr[d4.z], 1);
            if (d4.w >= lo && d4.w < hi) atomicAdd(&cntr[d4.w], 1);
        }
    }
}

__global__ __launch_bounds__(256) void k_scan1(const int* __restrict__ cnt, int* __restrict__ bsum)
{
    __shared__ int lds[256];
    int b = blockIdx.x, t = threadIdx.x;
    int base = b * 1024 + t * 4;
    int4 v = make_int4(0, 0, 0, 0);
    if (base < SCAN_M) v = *(const int4*)&cnt[base];
    lds[t] = v.x + v.y + v.z + v.w;
    __syncthreads();
    for (int o = 128; o > 0; o >>= 1) {
        if (t < o) lds[t] += lds[t + o];
        __syncthreads();
    }
    if (t == 0) bsum[b] = lds[0];
}

__global__ __launch_bounds__(512) void k_scan2(int* __restrict__ bsum)
{
    __shared__ int lds[512];
    int t = threadIdx.x;
    int v = t < SCAN_NB ? bsum[t] : 0;
    lds[t] = v;
    __syncthreads();
    for (int o = 1; o < 512; o <<= 1) {
        int add = t >= o ? lds[t - o] : 0;
        __syncthreads();
        lds[t] += add;
        __syncthreads();
    }
    if (t < SCAN_NB) bsum[t] = lds[t] - v;
}

__global__ __launch_bounds__(256) void k_scan3(
    const int* __restrict__ cnt, const int* __restrict__ bsum,
    int* __restrict__ off, int* __restrict__ woff)
{
    __shared__ int lds[256];
    int b = blockIdx.x, t = threadIdx.x;
    int base = b * 1024 + t * 4;
    int4 v = make_int4(0, 0, 0, 0);
    if (base < SCAN_M) v = *(const int4*)&cnt[base];
    int p1 = v.x, p2 = p1 + v.y, p3 = p2 + v.z, p4 = p3 + v.w;
    lds[t] = p4;
    __syncthreads();
    for (int o = 1; o < 256; o <<= 1) {
        int add = t >= o ? lds[t - o] : 0;
        __syncthreads();
        lds[t] += add;
        __syncthreads();
    }
    int excl = lds[t] - p4;
    int b0 = bsum[b] + excl;
    if (base < SCAN_M) {
        int4 o4 = make_int4(b0, b0 + p1, b0 + p2, b0 + p3);
        *(int4*)&off[base] = o4;
        *(int4*)&woff[base] = o4;
    }
    if (b == 0 && t == 0) off[SCAN_M] = NR * NEDGE;
}

__global__ __launch_bounds__(256) void k_fill(
    const int* __restrict__ ei, int* __restrict__ woff, int* __restrict__ esrc)
{
    const int part = blockIdx.x & 7;
    const int chunk = blockIdx.x >> 3;
    const int r = blockIdx.y;
    const int lo = part * PSIZE, hi = lo + PSIZE;
    const int* __restrict__ srcp = ei + (size_t)r * 2 * NEDGE;
    const int* __restrict__ dstp = srcp + NEDGE;
    int* __restrict__ woffr = woff + r * NN;
    const int e0 = chunk * CHUNK + threadIdx.x * 4;
#pragma unroll
    for (int k = 0; k < CHUNK / 1024; ++k) {
        int e = e0 + k * 1024;
        if (e < NEDGE) {
            int4 d4 = *(const int4*)&dstp[e];
            int4 s4 = *(const int4*)&srcp[e];
            if (d4.x >= lo && d4.x < hi) esrc[atomicAdd(&woffr[d4.x], 1)] = s4.x;
            if (d4.y >= lo && d4.y < hi) esrc[atomicAdd(&woffr[d4.y], 1)] = s4.y;
            if (d4.z >= lo && d4.z < hi) esrc[atomicAdd(&woffr[d4.z], 1)] = s4.z;
            if (d4.w >= lo && d4.w < hi) esrc[atomicAdd(&woffr[d4.w], 1)] = s4.w;
        }
    }
}

// ---------------------------------------------------------------------------
// Gather v2: 16 lanes/node (4 nodes/wave), ushort8 h cols per lane.
// Batch 8 edges/chunk: issue all loads (MLP~16), chunk-max, one rescale/chunk.
// ---------------------------------------------------------------------------
__global__ __launch_bounds__(256) void k_gather(
    const int* __restrict__ off, const int* __restrict__ esrc,
    const float* __restrict__ elr, const unsigned short* __restrict__ h3,
    const float* __restrict__ bias, float* __restrict__ out,
    int r0, int r1, int initmode)
{
    int n = (blockIdx.x * 256 + threadIdx.x) >> 4;
    int l = threadIdx.x & 15;
    if (n >= NN) return;
    const int head = l >> 2;
    const int c = l * 8;
    float o[8];
#pragma unroll
    for (int k = 0; k < 8; ++k) o[k] = 0.f;

    for (int r = r0; r < r1; ++r) {
        const int pb = r * 8 + head * 2;
        const float ern = elr[(size_t)n * 32 + pb + 1];
        const unsigned short* __restrict__ hr = h3 + (size_t)(r - r0) * NN * HF;
        const int beg = off[r * NN + n], end = off[r * NN + n + 1];
        float m = -FLT_MAX, s = 0.f;
        float acc[8];
#pragma unroll
        for (int k = 0; k < 8; ++k) acc[k] = 0.f;

        for (int i = beg; i < end; i += 8) {
            const int cnt = end - i;
            int sn[8];
            float ev[8];
            ushort8_t hv[8];
#pragma unroll
            for (int j = 0; j < 8; ++j) {
                int idx = (j < cnt) ? i + j : beg;
                sn[j] = esrc[idx];
            }
#pragma unroll
            for (int j = 0; j < 8; ++j) {
                float e = elr[(size_t)sn[j] * 32 + pb] + ern;
                e = fmaxf(e, SLOPE * e);                       // leaky-relu
                ev[j] = (j < cnt) ? e : -FLT_MAX;
                hv[j] = *(const ushort8_t*)&hr[(size_t)sn[j] * HF + c];
            }
            float mc = fmaxf(fmaxf(fmaxf(ev[0], ev[1]), fmaxf(ev[2], ev[3])),
                             fmaxf(fmaxf(ev[4], ev[5]), fmaxf(ev[6], ev[7])));
            float mn = fmaxf(m, mc);
            float sc = __expf(m - mn);                         // first chunk: exp(-huge)=0
            s *= sc;
#pragma unroll
            for (int k = 0; k < 8; ++k) acc[k] *= sc;
            m = mn;
#pragma unroll
            for (int j = 0; j < 8; ++j) {
                float pw = __expf(ev[j] - m);
                s += pw;
#pragma unroll
                for (int k = 0; k < 8; ++k)
                    acc[k] = fmaf(pw, __uint_as_float((unsigned)hv[j][k] << 16), acc[k]);
            }
        }
        if (s > 0.f) {
            float inv = 1.f / s;
#pragma unroll
            for (int k = 0; k < 8; ++k) o[k] += acc[k] * inv;
        }
    }

    float* po = &out[(size_t)n * HF + c];
    if (initmode) {
#pragma unroll
        for (int k = 0; k < 8; ++k)
            o[k] += bias[c + k] + bias[HF + c + k] + bias[2 * HF + c + k];
        *(float4*)po       = make_float4(o[0], o[1], o[2], o[3]);
        *(float4*)(po + 4) = make_float4(o[4], o[5], o[6], o[7]);
    } else {
        float4 v0 = *(float4*)po, v1 = *(float4*)(po + 4);
        v0.x += o[0]; v0.y += o[1]; v0.z += o[2]; v0.w += o[3];
        v1.x += o[4]; v1.y += o[5]; v1.z += o[6]; v1.w += o[7];
        *(float4*)po = v0;
        *(float4*)(po + 4) = v1;
    }
}

__global__ __launch_bounds__(256) void k_bail(float* __restrict__ out)
{
    long long i = (long long)blockIdx.x * 256 + threadIdx.x;
    if (i < (long long)NN * HF) out[i] = 0.f;
}

extern "C" void kernel_launch(void* const* d_in, const int* in_sizes, int n_in,
                              void* d_out, int out_size, void* d_ws, size_t ws_size,
                              hipStream_t stream) {
    const float* x    = (const float*)d_in[0];
    const float* W    = (const float*)d_in[1];
    const float* al   = (const float*)d_in[2];
    const float* ar   = (const float*)d_in[3];
    const float* bias = (const float*)d_in[4];
    const int* ei     = (const int*)d_in[5];
    float* out = (float*)d_out;

    const size_t HPLANE = (size_t)NN * HF;            // elems (ushort)
    const size_t XP = (size_t)NMT * 256;              // short8 per plane
    const size_t BP = (size_t)24 * 4 * 64;            // short8 per plane
    const size_t fixed = XP * 16 * 2 + (size_t)NN * 32 * 4 + 24 * 128 * 4 + BP * 16 * 2
                       + (size_t)SCAN_M * 4 + (size_t)(SCAN_M + 4) * 4 + (size_t)SCAN_M * 4
                       + 4096 + (size_t)NR * NEDGE * 4;
    const size_t need_big = fixed + 3 * HPLANE * 2;
    const size_t need_small = fixed + HPLANE * 2;
    if (ws_size < need_small) {
        k_bail<<<(NN * HF + 255) / 256, 256, 0, stream>>>(out);
        return;
    }
    const bool big = ws_size >= need_big;
    const int hplanes = big ? 3 : 1;

    char* p = (char*)d_ws;
    unsigned short* h3 = (unsigned short*)p; p += (size_t)hplanes * HPLANE * 2;
    short8* xhi = (short8*)p; p += XP * 16;
    short8* xlo = (short8*)p; p += XP * 16;
    float*  elr = (float*)p;  p += (size_t)NN * 32 * 4;
    float*  v   = (float*)p;  p += 24 * 128 * 4;
    short8* bhi = (short8*)p; p += BP * 16;
    short8* blo = (short8*)p; p += BP * 16;
    int* cnt  = (int*)p; p += (size_t)SCAN_M * 4;
    int* off  = (int*)p; p += (size_t)(SCAN_M + 4) * 4;
    int* woff = (int*)p; p += (size_t)SCAN_M * 4;
    int* bsum = (int*)p; p += 4096;
    int* esrc = (int*)p; p += (size_t)NR * NEDGE * 4;

    // prep: v, W-pack, x-pack + elr
    k_prep0<<<24, 128, 0, stream>>>(W, al, ar, v);
    k_bpack<<<24, 256, 0, stream>>>(W, bhi, blo);
    k_prep<<<NMT, 256, 0, stream>>>(x, v, xhi, xlo, elr);

    // CSR build
    hipMemsetAsync(cnt, 0, (size_t)SCAN_M * 4, stream);
    dim3 pgrid(NCHUNK * NPART, NR);
    k_count<<<pgrid, 256, 0, stream>>>(ei, cnt);
    k_scan1<<<SCAN_NB, 256, 0, stream>>>(cnt, bsum);
    k_scan2<<<1, 512, 0, stream>>>(bsum);
    k_scan3<<<SCAN_NB, 256, 0, stream>>>(cnt, bsum, off, woff);
    k_fill<<<pgrid, 256, 0, stream>>>(ei, woff, esrc);

    int gblocks = (NN * 16 + 255) / 256;
    if (big) {
        dim3 mmg(MB, 3);
        k_mm<<<mmg, 256, 0, stream>>>(xhi, xlo, bhi, blo, h3, 0);
        k_gather<<<gblocks, 256, 0, stream>>>(off, esrc, elr, h3, bias, out, 0, 3, 1);
    } else {
        for (int r = 0; r < NR; ++r) {
            dim3 mmg(MB, 1);
            k_mm<<<mmg, 256, 0, stream>>>(xhi, xlo, bhi, blo, h3, r * 8);
            k_gather<<<gblocks, 256, 0, stream>>>(off, esrc, elr, h3, bias, out,
                                                  r, r + 1, r == 0 ? 1 : 0);
        }
    }
}